// Round 1
// baseline (1448.292 us; speedup 1.0000x reference)
//
#include <hip/hip_runtime.h>

// Problem constants (shapes fixed by the reference)
#define HP    1017
#define WP    1017
#define NPIX  (HP*WP)          // 1034289
#define N3    (NPIX/3)         // 344763 (NPIX divisible by 3)
#define W_IMG 1024
#define RATE  0.001f
#define EPSV  1e-7f

// ---------------------------------------------------------------------------
// init: t0 = tlb = max_c(1 - center/A), and pack img_c = img[:HP,:WP,:] contiguously
// ---------------------------------------------------------------------------
__global__ void init_kernel(const float* __restrict__ img, const float* __restrict__ A,
                            float* __restrict__ img_c, float* __restrict__ t0) {
    int b = blockIdx.x * blockDim.x + threadIdx.x;
    int a = blockIdx.y;
    if (b >= WP) return;
    int m = a * WP + b;
    float A0 = A[0], A1 = A[1], A2 = A[2];
    const float* src = img + ((size_t)a * W_IMG + b) * 3;
    float c0 = src[0], c1 = src[1], c2 = src[2];
    img_c[3*m+0] = c0; img_c[3*m+1] = c1; img_c[3*m+2] = c2;
    const float* cen = img + ((size_t)(a+3) * W_IMG + (b+3)) * 3;
    float t = 1.0f - cen[0] / A0;
    t = fmaxf(t, 1.0f - cen[1] / A1);
    t = fmaxf(t, 1.0f - cen[2] / A2);
    t0[m] = t;
}

// ---------------------------------------------------------------------------
// sig: compute sig = sigmoid(-48*(l2-0.1)) from dehaze(t), where the "gradient"
// is a central diff along the FLAT index of the dehazed (N,3) image,
// with one-sided diffs at flat positions {0, N-1, N, 2N-1, 2N, 3N-1}.
// Also store lg = log(guard(t)) for the update kernel.
// ---------------------------------------------------------------------------
__global__ void sig_kernel(const float* __restrict__ t, const float* __restrict__ img_c,
                           const float* __restrict__ A,
                           float* __restrict__ sig, float* __restrict__ lgarr) {
    int m = blockIdx.x * blockDim.x + threadIdx.x;
    if (m >= NPIX) return;
    float A0 = A[0], A1 = A[1], A2 = A[2];
    float t0 = t[m];
    float tm = t[m > 0 ? m - 1 : 0];
    float tp = t[m < NPIX-1 ? m + 1 : NPIX-1];
    float r0 = 1.0f / t0, rm = 1.0f / tm, rp = 1.0f / tp;
    int base = 3 * m;
    float fm1 = img_c[m > 0        ? base - 1 : 0];
    float f0  = img_c[base + 0];
    float f1  = img_c[base + 1];
    float f2  = img_c[base + 2];
    float f3  = img_c[m < NPIX - 1 ? base + 3 : base + 2];
    // dehazed flat values at q = 3m-1 .. 3m+3 (channel = q % 3)
    float dm1 = (fm1 - A2) * rm + A2;   // q=3m-1, ch2, pixel m-1
    float d0  = (f0  - A0) * r0 + A0;   // q=3m,   ch0
    float d1  = (f1  - A1) * r0 + A1;   // q=3m+1, ch1
    float d2  = (f2  - A2) * r0 + A2;   // q=3m+2, ch2
    float d3  = (f3  - A0) * rp + A0;   // q=3m+3, ch0, pixel m+1
    float y0 = 0.5f * (d1 - dm1);
    float y1 = 0.5f * (d2 - d0);
    float y2 = 0.5f * (d3 - d1);
    // one-sided boundary fixes (rows of the (3,N) reshape)
    if (m == 0      ) y0 = d1 - d0;     // q = 0
    if (m == N3     ) y0 = d1 - d0;     // q = N
    if (m == 2*N3   ) y0 = d1 - d0;     // q = 2N
    if (m == N3 - 1 ) y2 = d2 - d1;     // q = N-1
    if (m == 2*N3-1 ) y2 = d2 - d1;     // q = 2N-1
    if (m == NPIX-1 ) y2 = d2 - d1;     // q = 3N-1
    float l2 = sqrtf(y0*y0 + y1*y1 + y2*y2);
    float s  = 1.0f / (1.0f + expf(48.0f * (l2 - 0.1f)));
    sig[m] = s;
    lgarr[m] = logf(t0 <= 0.0f ? EPSV : t0);
}

// ---------------------------------------------------------------------------
// update: gradient of sum((dx^2+dy^2)*sig) wrt w, t_new = w0 - RATE*g
// dx[i][j] = LG(i,j+1)-LG(i,j-1), dy[i][j] = LG(i-1,j)-LG(i+1,j), LG=0 outside.
// g[a][b] = 2*( [b>=1]   dx[a][b-1]*sig[a][b-1]
//             - [b<=W-2] dx[a][b+1]*sig[a][b+1]
//             + [a<=H-2] dy[a+1][b]*sig[a+1][b]
//             - [a>=1]   dy[a-1][b]*sig[a-1][b] ) / w0
// ---------------------------------------------------------------------------
__global__ void update_kernel(const float* __restrict__ t, const float* __restrict__ lg,
                              const float* __restrict__ sig, float* __restrict__ tout) {
    int b = blockIdx.x * blockDim.x + threadIdx.x;
    int a = blockIdx.y;
    if (b >= WP) return;
    int m = a * WP + b;
    float tc = t[m];
    float w0 = (tc <= 0.0f) ? EPSV : tc;
    float lgC = lg[m];
    float acc = 0.0f;
    if (b >= 1) {
        float lgW = (b >= 2) ? lg[m-2] : 0.0f;
        acc += (lgC - lgW) * sig[m-1];          // +dx[a][b-1]*sig[a][b-1]
    }
    if (b <= WP-2) {
        float lgE = (b <= WP-3) ? lg[m+2] : 0.0f;
        acc -= (lgE - lgC) * sig[m+1];          // -dx[a][b+1]*sig[a][b+1]
    }
    if (a <= HP-2) {
        float lgS = (a <= HP-3) ? lg[m+2*WP] : 0.0f;
        acc += (lgC - lgS) * sig[m+WP];         // +dy[a+1][b]*sig[a+1][b]
    }
    if (a >= 1) {
        float lgN = (a >= 2) ? lg[m-2*WP] : 0.0f;
        acc -= (lgN - lgC) * sig[m-WP];         // -dy[a-1][b]*sig[a-1][b]
    }
    float g = 2.0f * acc / w0;
    tout[m] = w0 - RATE * g;
}

// ---------------------------------------------------------------------------
// final dehaze into d_out
// ---------------------------------------------------------------------------
__global__ void out_kernel(const float* __restrict__ t, const float* __restrict__ img_c,
                           const float* __restrict__ A, float* __restrict__ out) {
    int m = blockIdx.x * blockDim.x + threadIdx.x;
    if (m >= NPIX) return;
    float tv = t[m];
    float A0 = A[0], A1 = A[1], A2 = A[2];
    out[3*m+0] = (img_c[3*m+0] - A0) / tv + A0;
    out[3*m+1] = (img_c[3*m+1] - A1) / tv + A1;
    out[3*m+2] = (img_c[3*m+2] - A2) / tv + A2;
}

extern "C" void kernel_launch(void* const* d_in, const int* in_sizes, int n_in,
                              void* d_out, int out_size, void* d_ws, size_t ws_size,
                              hipStream_t stream) {
    const float* img = (const float*)d_in[0];
    const float* A   = (const float*)d_in[1];
    // workspace layout (floats): img_c[3N] | t_a[N] | t_b[N] | sig[N] | lg[N]  = 7N ~ 28MB
    float* ws    = (float*)d_ws;
    float* img_c = ws;
    float* t_a   = ws + (size_t)3 * NPIX;
    float* t_b   = t_a + NPIX;
    float* sig   = t_b + NPIX;
    float* lg    = sig + NPIX;

    dim3 blk2(256, 1, 1);
    dim3 grd2((WP + 255) / 256, HP, 1);
    int blk1 = 256;
    int grd1 = (NPIX + blk1 - 1) / blk1;

    hipLaunchKernelGGL(init_kernel, grd2, blk2, 0, stream, img, A, img_c, t_a);
    hipLaunchKernelGGL(sig_kernel, dim3(grd1), dim3(blk1), 0, stream, t_a, img_c, A, sig, lg);

    float* tsrc = t_a;
    float* tdst = t_b;
    for (int it = 0; it < 100; ++it) {
        hipLaunchKernelGGL(update_kernel, grd2, blk2, 0, stream, tsrc, lg, sig, tdst);
        if (it < 99)
            hipLaunchKernelGGL(sig_kernel, dim3(grd1), dim3(blk1), 0, stream, tdst, img_c, A, sig, lg);
        float* tmp = tsrc; tsrc = tdst; tdst = tmp;
    }
    // after the final swap, tsrc holds t_final
    hipLaunchKernelGGL(out_kernel, dim3(grd1), dim3(blk1), 0, stream, tsrc, img_c, A, (float*)d_out);
}